// Round 5
// baseline (866.025 us; speedup 1.0000x reference)
//
#include <hip/hip_runtime.h>
#include <cstdint>

#define T_TOK 512
#define H_DIM 2048
#define I_DIM 1408
#define N_EXP 16

typedef __attribute__((ext_vector_type(8))) _Float16 f16x8;
typedef __attribute__((ext_vector_type(4))) float f32x4;

__device__ __forceinline__ f16x8 cvt8(f32x4 a, f32x4 b) {
  f16x8 r;
  r[0] = (_Float16)a[0]; r[1] = (_Float16)a[1]; r[2] = (_Float16)a[2]; r[3] = (_Float16)a[3];
  r[4] = (_Float16)b[0]; r[5] = (_Float16)b[1]; r[6] = (_Float16)b[2]; r[7] = (_Float16)b[3];
  return r;
}

// ---------------- kernel 1: routing + x -> fp16 ----------------
__global__ __launch_bounds__(256) void route_kernel(
    const float* __restrict__ x, const float* __restrict__ gw,
    const float* __restrict__ bias, float* __restrict__ coef,
    _Float16* __restrict__ xb) {
  const int t = blockIdx.x;
  const int tid = threadIdx.x;
  const float* xt = x + (size_t)t * H_DIM;
  _Float16* xbt = xb + (size_t)t * H_DIM;

  float part[N_EXP];
#pragma unroll
  for (int e = 0; e < N_EXP; ++e) part[e] = 0.f;
  for (int j = tid; j < H_DIM; j += 256) {
    float xv = xt[j];
    xbt[j] = (_Float16)xv;
#pragma unroll
    for (int e = 0; e < N_EXP; ++e) part[e] += xv * gw[e * H_DIM + j];
  }
#pragma unroll
  for (int e = 0; e < N_EXP; ++e) {
#pragma unroll
    for (int off = 32; off > 0; off >>= 1) part[e] += __shfl_down(part[e], off);
  }
  __shared__ float red[4][N_EXP];
  const int lane = tid & 63, w = tid >> 6;
  if (lane == 0) {
#pragma unroll
    for (int e = 0; e < N_EXP; ++e) red[w][e] = part[e];
  }
  __syncthreads();
  if (tid == 0) {
    float s[16], sf[16];
    for (int e = 0; e < 16; ++e) {
      float lg = red[0][e] + red[1][e] + red[2][e] + red[3][e];
      s[e] = 1.f / (1.f + expf(-lg));
      sf[e] = s[e] + bias[e];
    }
    float gsc[4];
    for (int g = 0; g < 4; ++g) {
      float m1 = -1e30f, m2 = -1e30f;
      for (int j = 0; j < 4; ++j) {
        float v = sf[g * 4 + j];
        if (v > m1) { m2 = m1; m1 = v; }
        else if (v > m2) { m2 = v; }
      }
      gsc[g] = m1 + m2;
    }
    int g1 = 0;
    for (int g = 1; g < 4; ++g) if (gsc[g] > gsc[g1]) g1 = g;
    int g2 = -1;
    for (int g = 0; g < 4; ++g) {
      if (g == g1) continue;
      if (g2 < 0 || gsc[g] > gsc[g2]) g2 = g;
    }
    bool gok[4];
    for (int g = 0; g < 4; ++g) gok[g] = (g == g1) || (g == g2);
    bool sel[16];
    for (int e = 0; e < 16; ++e) sel[e] = false;
    float wsum = 0.f;
    for (int k = 0; k < 6; ++k) {
      int best = -1; float bv = 0.f;
      for (int e2 = 0; e2 < 16; ++e2) {
        if (!gok[e2 >> 2] || sel[e2]) continue;
        if (best < 0 || sf[e2] > bv) { bv = sf[e2]; best = e2; }
      }
      sel[best] = true;
      wsum += s[best];
    }
    float inv = 2.5f / wsum;
    for (int e = 0; e < 16; ++e) coef[t * N_EXP + e] = sel[e] ? s[e] * inv : 0.f;
  }
}

// ---------------- kernel 2: per-expert token lists ----------------
__global__ __launch_bounds__(512) void build_lists_kernel(
    const float* __restrict__ coef, int* __restrict__ counts,
    int* __restrict__ lists) {
  const int e = blockIdx.x;
  const int t = threadIdx.x;
  const bool flag = coef[t * N_EXP + e] != 0.f;
  const unsigned long long m = __ballot(flag);
  const int lane = t & 63, w = t >> 6;
  __shared__ int wcnt[8], woff[8];
  if (lane == 0) wcnt[w] = __popcll(m);
  __syncthreads();
  if (t == 0) {
    int a = 0;
    for (int i = 0; i < 8; ++i) { woff[i] = a; a += wcnt[i]; }
    counts[e] = a;
  }
  __syncthreads();
  if (flag) {
    int pos = woff[w] + __popcll(m & ((1ull << lane) - 1ull));
    lists[e * T_TOK + pos] = t;
  }
}

// ---------------- kernel 3: gate+up, wave-independent register GEMM ----------
// wave tile: 64 rows x 32 I-cols, both matrices. No LDS, no barriers.
// work id: rb (8, fastest) x strip (44) x expert (16) = 5632 waves, 1408 blocks.
// XCD-chunk remap keeps one (strip,e) group on one XCD; 4 waves of a block
// share B columns -> L1 reuse.
__global__ __launch_bounds__(256, 2) void gate_up_kernel(
    const _Float16* __restrict__ xb, const float* __restrict__ wg,
    const float* __restrict__ wu, const int* __restrict__ counts,
    const int* __restrict__ lists, _Float16* __restrict__ hbuf) {
  const int tid = threadIdx.x;
  const int lane = tid & 63;
  const int bx = blockIdx.x;                 // 0..1407
  const int wb = (bx & 7) * 176 + (bx >> 3); // XCD-chunked work block
  const int wid = wb * 4 + (tid >> 6);       // 0..5631
  const int rb = wid & 7;
  const int strip = (wid >> 3) % 44;
  const int e = wid / 352;
  const int ne = counts[e];
  const int row0 = rb * 64;
  if (row0 >= ne) return;

  const int* lst = lists + e * T_TOK;
  const _Float16* ap[4];
#pragma unroll
  for (int m = 0; m < 4; ++m) {
    int r = row0 + m * 16 + (lane & 15);
    int tok = lst[min(r, ne - 1)];
    ap[m] = xb + (size_t)tok * H_DIM + (lane >> 4) * 8;
  }
  const int col0 = strip * 32;
  const float* gp[2];
  const float* up[2];
#pragma unroll
  for (int n = 0; n < 2; ++n) {
    size_t off = ((size_t)e * I_DIM + col0 + n * 16 + (lane & 15)) * H_DIM + (lane >> 4) * 8;
    gp[n] = wg + off;
    up[n] = wu + off;
  }

  f32x4 accg[4][2], accu[4][2];
  const f32x4 zz = {0.f, 0.f, 0.f, 0.f};
#pragma unroll
  for (int m = 0; m < 4; ++m)
#pragma unroll
    for (int n = 0; n < 2; ++n) { accg[m][n] = zz; accu[m][n] = zz; }

  auto loadA = [&](f16x8 (&ab)[4], int k0) {
#pragma unroll
    for (int m = 0; m < 4; ++m) ab[m] = *(const f16x8*)(ap[m] + k0);
  };
  auto loadB = [&](f32x4 (&gb)[2][2], f32x4 (&ub)[2][2], int k0) {
#pragma unroll
    for (int n = 0; n < 2; ++n) {
      gb[n][0] = *(const f32x4*)(gp[n] + k0);
      gb[n][1] = *(const f32x4*)(gp[n] + k0 + 4);
      ub[n][0] = *(const f32x4*)(up[n] + k0);
      ub[n][1] = *(const f32x4*)(up[n] + k0 + 4);
    }
  };
  auto compute = [&](f16x8 (&ab)[4], f32x4 (&gb)[2][2], f32x4 (&ub)[2][2]) {
    f16x8 bg[2], bu[2];
#pragma unroll
    for (int n = 0; n < 2; ++n) {
      bg[n] = cvt8(gb[n][0], gb[n][1]);
      bu[n] = cvt8(ub[n][0], ub[n][1]);
    }
#pragma unroll
    for (int m = 0; m < 4; ++m)
#pragma unroll
      for (int n = 0; n < 2; ++n) {
        accg[m][n] = __builtin_amdgcn_mfma_f32_16x16x32_f16(ab[m], bg[n], accg[m][n], 0, 0, 0);
        accu[m][n] = __builtin_amdgcn_mfma_f32_16x16x32_f16(ab[m], bu[n], accu[m][n], 0, 0, 0);
      }
  };

  f16x8 a0[4], a1[4];
  f32x4 g0[2][2], u0[2][2], g1[2][2], u1[2][2];
  loadA(a0, 0); loadB(g0, u0, 0);
  for (int kt = 0; kt < H_DIM / 32; kt += 2) {
    loadA(a1, (kt + 1) * 32); loadB(g1, u1, (kt + 1) * 32);
    compute(a0, g0, u0);
    if (kt + 2 < H_DIM / 32) { loadA(a0, (kt + 2) * 32); loadB(g0, u0, (kt + 2) * 32); }
    compute(a1, g1, u1);
  }

  // epilogue: silu(g)*u -> fp16 h
  const int rr = (lane >> 4) * 4;
  const int cc = col0 + (lane & 15);
  _Float16* hb = hbuf + (size_t)e * T_TOK * I_DIM;
#pragma unroll
  for (int m = 0; m < 4; ++m) {
#pragma unroll
    for (int j = 0; j < 4; ++j) {
      int r = row0 + m * 16 + rr + j;
      if (r < ne) {
#pragma unroll
        for (int n = 0; n < 2; ++n) {
          float g = accg[m][n][j];
          float u = accu[m][n][j];
          float hv = (g / (1.f + __expf(-g))) * u;
          hb[(size_t)r * I_DIM + cc + n * 16] = (_Float16)hv;
        }
      }
    }
  }
}

// ---------------- kernel 4: down GEMM, wave-independent + scatter-add -------
// wave tile: 64 rows x 32 H-cols. work: rb(8) x cstrip(64) x expert(16) = 8192
__global__ __launch_bounds__(256, 3) void down_kernel(
    const _Float16* __restrict__ hbuf, const float* __restrict__ wd,
    const int* __restrict__ counts, const int* __restrict__ lists,
    const float* __restrict__ coef, float* __restrict__ out) {
  const int tid = threadIdx.x;
  const int lane = tid & 63;
  const int bx = blockIdx.x;                 // 0..2047
  const int wb = (bx & 7) * 256 + (bx >> 3);
  const int wid = wb * 4 + (tid >> 6);       // 0..8191
  const int rb = wid & 7;
  const int cs = (wid >> 3) & 63;
  const int e = wid >> 9;
  const int ne = counts[e];
  const int row0 = rb * 64;
  if (row0 >= ne) return;

  const _Float16* hb = hbuf + (size_t)e * T_TOK * I_DIM;
  const _Float16* ap[4];
#pragma unroll
  for (int m = 0; m < 4; ++m) {
    int r = row0 + m * 16 + (lane & 15);     // < 512 always
    ap[m] = hb + (size_t)r * I_DIM + (lane >> 4) * 8;
  }
  const int col0 = cs * 32;
  const float* bp[2];
#pragma unroll
  for (int n = 0; n < 2; ++n)
    bp[n] = wd + ((size_t)e * H_DIM + col0 + n * 16 + (lane & 15)) * I_DIM + (lane >> 4) * 8;

  f32x4 acc[4][2];
  const f32x4 zz = {0.f, 0.f, 0.f, 0.f};
#pragma unroll
  for (int m = 0; m < 4; ++m)
#pragma unroll
    for (int n = 0; n < 2; ++n) acc[m][n] = zz;

  auto loadA = [&](f16x8 (&ab)[4], int k0) {
#pragma unroll
    for (int m = 0; m < 4; ++m) ab[m] = *(const f16x8*)(ap[m] + k0);
  };
  auto loadB = [&](f32x4 (&bb)[2][2], int k0) {
#pragma unroll
    for (int n = 0; n < 2; ++n) {
      bb[n][0] = *(const f32x4*)(bp[n] + k0);
      bb[n][1] = *(const f32x4*)(bp[n] + k0 + 4);
    }
  };
  auto compute = [&](f16x8 (&ab)[4], f32x4 (&bb)[2][2]) {
    f16x8 bf[2];
#pragma unroll
    for (int n = 0; n < 2; ++n) bf[n] = cvt8(bb[n][0], bb[n][1]);
#pragma unroll
    for (int m = 0; m < 4; ++m)
#pragma unroll
      for (int n = 0; n < 2; ++n)
        acc[m][n] = __builtin_amdgcn_mfma_f32_16x16x32_f16(ab[m], bf[n], acc[m][n], 0, 0, 0);
  };

  f16x8 a0[4], a1[4];
  f32x4 b0[2][2], b1[2][2];
  loadA(a0, 0); loadB(b0, 0);
  for (int kt = 0; kt < I_DIM / 32; kt += 2) {
    loadA(a1, (kt + 1) * 32); loadB(b1, (kt + 1) * 32);
    compute(a0, b0);
    if (kt + 2 < I_DIM / 32) { loadA(a0, (kt + 2) * 32); loadB(b0, (kt + 2) * 32); }
    compute(a1, b1);
  }

  const int rr = (lane >> 4) * 4;
  const int cc = col0 + (lane & 15);
#pragma unroll
  for (int m = 0; m < 4; ++m) {
#pragma unroll
    for (int j = 0; j < 4; ++j) {
      int r = row0 + m * 16 + rr + j;
      if (r < ne) {
        int tok = lists[e * T_TOK + r];
        float c = coef[tok * N_EXP + e];
#pragma unroll
        for (int n = 0; n < 2; ++n)
          atomicAdd(&out[(size_t)tok * H_DIM + cc + n * 16], acc[m][n][j] * c);
      }
    }
  }
}

// ---------------- launch ----------------
extern "C" void kernel_launch(void* const* d_in, const int* in_sizes, int n_in,
                              void* d_out, int out_size, void* d_ws, size_t ws_size,
                              hipStream_t stream) {
  const float* x  = (const float*)d_in[0];
  const float* gw = (const float*)d_in[1];
  const float* cb = (const float*)d_in[2];
  const float* wg = (const float*)d_in[3];
  const float* wu = (const float*)d_in[4];
  const float* wd = (const float*)d_in[5];
  float* out = (float*)d_out;
  char* ws = (char*)d_ws;

  float* coef   = (float*)(ws);                    // 512*16*4 = 32768
  int*   counts = (int*)(ws + 32768);              // 64 B
  int*   lists  = (int*)(ws + 33024);              // 16*512*4 = 32768
  _Float16* xb  = (_Float16*)(ws + 66048);         // 512*2048*2 = 2 MiB
  _Float16* hbuf= (_Float16*)(ws + 66048 + 2097152 + 256); // 16*512*1408*2 = 23 MiB

  hipMemsetAsync(d_out, 0, (size_t)out_size * sizeof(float), stream);

  route_kernel<<<T_TOK, 256, 0, stream>>>(x, gw, cb, coef, xb);
  build_lists_kernel<<<N_EXP, 512, 0, stream>>>(coef, counts, lists);
  gate_up_kernel<<<1408, 256, 0, stream>>>(xb, wg, wu, counts, lists, hbuf);
  down_kernel<<<2048, 256, 0, stream>>>(hbuf, wd, counts, lists, coef, out);
}

// Round 6
// 263.998 us; speedup vs baseline: 3.2804x; 3.2804x over previous
//
#include <hip/hip_runtime.h>
#include <cstdint>

#define T_TOK 512
#define H_DIM 2048
#define I_DIM 1408
#define N_EXP 16

typedef __attribute__((ext_vector_type(8))) _Float16 f16x8;
typedef __attribute__((ext_vector_type(4))) float f32x4;

__device__ __forceinline__ void gload_lds16(const void* g, void* l) {
  auto gp = (const __attribute__((address_space(1))) unsigned int*)(unsigned long long)g;
  unsigned int loff = (unsigned int)(unsigned long long)l;
  auto lp = (__attribute__((address_space(3))) unsigned int*)loff;
  __builtin_amdgcn_global_load_lds(gp, lp, 16, 0, 0);
}

__device__ __forceinline__ f16x8 cvt8(f32x4 a, f32x4 b) {
  f16x8 r;
  r[0] = (_Float16)a[0]; r[1] = (_Float16)a[1]; r[2] = (_Float16)a[2]; r[3] = (_Float16)a[3];
  r[4] = (_Float16)b[0]; r[5] = (_Float16)b[1]; r[6] = (_Float16)b[2]; r[7] = (_Float16)b[3];
  return r;
}

// ---------------- kernel 1: routing + x -> fp16 ----------------
__global__ __launch_bounds__(256) void route_kernel(
    const float* __restrict__ x, const float* __restrict__ gw,
    const float* __restrict__ bias, float* __restrict__ coef,
    _Float16* __restrict__ xb) {
  const int t = blockIdx.x;
  const int tid = threadIdx.x;
  const float* xt = x + (size_t)t * H_DIM;
  _Float16* xbt = xb + (size_t)t * H_DIM;

  float part[N_EXP];
#pragma unroll
  for (int e = 0; e < N_EXP; ++e) part[e] = 0.f;
  for (int j = tid; j < H_DIM; j += 256) {
    float xv = xt[j];
    xbt[j] = (_Float16)xv;
#pragma unroll
    for (int e = 0; e < N_EXP; ++e) part[e] += xv * gw[e * H_DIM + j];
  }
#pragma unroll
  for (int e = 0; e < N_EXP; ++e) {
#pragma unroll
    for (int off = 32; off > 0; off >>= 1) part[e] += __shfl_down(part[e], off);
  }
  __shared__ float red[4][N_EXP];
  const int lane = tid & 63, w = tid >> 6;
  if (lane == 0) {
#pragma unroll
    for (int e = 0; e < N_EXP; ++e) red[w][e] = part[e];
  }
  __syncthreads();
  if (tid == 0) {
    float s[16], sf[16];
    for (int e = 0; e < 16; ++e) {
      float lg = red[0][e] + red[1][e] + red[2][e] + red[3][e];
      s[e] = 1.f / (1.f + expf(-lg));
      sf[e] = s[e] + bias[e];
    }
    float gsc[4];
    for (int g = 0; g < 4; ++g) {
      float m1 = -1e30f, m2 = -1e30f;
      for (int j = 0; j < 4; ++j) {
        float v = sf[g * 4 + j];
        if (v > m1) { m2 = m1; m1 = v; }
        else if (v > m2) { m2 = v; }
      }
      gsc[g] = m1 + m2;
    }
    int g1 = 0;
    for (int g = 1; g < 4; ++g) if (gsc[g] > gsc[g1]) g1 = g;
    int g2 = -1;
    for (int g = 0; g < 4; ++g) {
      if (g == g1) continue;
      if (g2 < 0 || gsc[g] > gsc[g2]) g2 = g;
    }
    bool gok[4];
    for (int g = 0; g < 4; ++g) gok[g] = (g == g1) || (g == g2);
    bool sel[16];
    for (int e = 0; e < 16; ++e) sel[e] = false;
    float wsum = 0.f;
    for (int k = 0; k < 6; ++k) {
      int best = -1; float bv = 0.f;
      for (int e2 = 0; e2 < 16; ++e2) {
        if (!gok[e2 >> 2] || sel[e2]) continue;
        if (best < 0 || sf[e2] > bv) { bv = sf[e2]; best = e2; }
      }
      sel[best] = true;
      wsum += s[best];
    }
    float inv = 2.5f / wsum;
    for (int e = 0; e < 16; ++e) coef[t * N_EXP + e] = sel[e] ? s[e] * inv : 0.f;
  }
}

// ---------------- kernel 2: per-expert token lists ----------------
__global__ __launch_bounds__(512) void build_lists_kernel(
    const float* __restrict__ coef, int* __restrict__ counts,
    int* __restrict__ lists) {
  const int e = blockIdx.x;
  const int t = threadIdx.x;
  const bool flag = coef[t * N_EXP + e] != 0.f;
  const unsigned long long m = __ballot(flag);
  const int lane = t & 63, w = t >> 6;
  __shared__ int wcnt[8], woff[8];
  if (lane == 0) wcnt[w] = __popcll(m);
  __syncthreads();
  if (t == 0) {
    int a = 0;
    for (int i = 0; i < 8; ++i) { woff[i] = a; a += wcnt[i]; }
    counts[e] = a;
  }
  __syncthreads();
  if (flag) {
    int pos = woff[w] + __popcll(m & ((1ull << lane) - 1ull));
    lists[e * T_TOK + pos] = t;
  }
}

// ---------------- kernel 3: gate+up GEMM, counted-vmcnt 2-lead pipeline -----
// BM=256, BN=128, BK=32, 512 thr / 8 waves (4 wr x 2 wc), wave tile 64x64.
// A: gload_lds frag-linear, 1-iter lead. B: reg-staged float4 (2-iter lead),
// cvt->f16, XOR-swizzled ds_write. vmcnt(6) steady state.
__global__ __launch_bounds__(512, 2) void gate_up_kernel(
    const _Float16* __restrict__ xb, const float* __restrict__ wg,
    const float* __restrict__ wu, const int* __restrict__ counts,
    const int* __restrict__ lists, _Float16* __restrict__ hbuf) {
  const int e = blockIdx.z;
  const int ne = counts[e];
  const int row0 = blockIdx.y * 256;
  if (row0 >= ne) return;
  const int col0 = blockIdx.x * 128;
  const int tid = threadIdx.x;
  const int lane = tid & 63;
  const int w = tid >> 6;
  const int wr = w >> 1, wc = w & 1;

  __shared__ _Float16 Als[2][256 * 32];        // 2 x 16 KB, frag-linear
  __shared__ _Float16 Bls[2][2][128 * 32];     // 2 buf x {g,u} x 8 KB

  // A gather sources: wave w stages m-blocks 2w, 2w+1
  const int* lst = lists + e * T_TOK;
  const _Float16* ap0;
  const _Float16* ap1;
  {
    int r0 = row0 + (2 * w) * 16 + (lane & 15);
    int r1 = r0 + 16;
    ap0 = xb + (size_t)lst[min(r0, ne - 1)] * H_DIM + (lane >> 4) * 8;
    ap1 = xb + (size_t)lst[min(r1, ne - 1)] * H_DIM + (lane >> 4) * 8;
  }
  const int adst0 = (2 * w) * 512 + lane * 8;
  const int adst1 = adst0 + 512;

  // B sources: thread t -> B-row r (I-col), k-quarter q
  const int br = tid >> 2;          // 0..127
  const int bq = tid & 3;           // 0..3
  const float* bgp = wg + ((size_t)e * I_DIM + col0 + br) * H_DIM + bq * 8;
  const float* bup = wu + ((size_t)e * I_DIM + col0 + br) * H_DIM + bq * 8;
  const int woff = (br * 32 + bq * 8) ^ ((br & 7) << 3);

  f32x4 accg[4][4], accu[4][4];
  const f32x4 zz = {0.f, 0.f, 0.f, 0.f};
#pragma unroll
  for (int m = 0; m < 4; ++m)
#pragma unroll
    for (int n = 0; n < 4; ++n) { accg[m][n] = zz; accu[m][n] = zz; }

  auto issueA = [&](int kt, int b) {
    gload_lds16(ap0 + kt * 32, &Als[b][adst0]);
    gload_lds16(ap1 + kt * 32, &Als[b][adst1]);
  };
  auto comp = [&](int b) {
    f16x8 afr[4], bg[4], bu[4];
#pragma unroll
    for (int m = 0; m < 4; ++m)
      afr[m] = *(const f16x8*)&Als[b][(wr * 4 + m) * 512 + lane * 8];
    const int sg = lane >> 4;
#pragma unroll
    for (int n = 0; n < 4; ++n) {
      const int c = wc * 64 + n * 16 + (lane & 15);
      const int off = (c * 32 + sg * 8) ^ ((c & 7) << 3);
      bg[n] = *(const f16x8*)&Bls[b][0][off];
      bu[n] = *(const f16x8*)&Bls[b][1][off];
    }
#pragma unroll
    for (int m = 0; m < 4; ++m)
#pragma unroll
      for (int n = 0; n < 4; ++n) {
        accg[m][n] = __builtin_amdgcn_mfma_f32_16x16x32_f16(afr[m], bg[n], accg[m][n], 0, 0, 0);
        accu[m][n] = __builtin_amdgcn_mfma_f32_16x16x32_f16(afr[m], bu[n], accu[m][n], 0, 0, 0);
      }
  };

  const int NK = H_DIM / 32;   // 64
  // B reg slots (named, static)
  f32x4 g0a, g0b, u0a, u0b, g1a, g1b, u1a, u1b;

  // prologue: B(0)->slot0, A(0)->Als[0], B(1)->slot1
  g0a = *(const f32x4*)(bgp);     g0b = *(const f32x4*)(bgp + 4);
  u0a = *(const f32x4*)(bup);     u0b = *(const f32x4*)(bup + 4);
  issueA(0, 0);
  g1a = *(const f32x4*)(bgp + 32); g1b = *(const f32x4*)(bgp + 36);
  u1a = *(const f32x4*)(bup + 32); u1b = *(const f32x4*)(bup + 36);
  asm volatile("s_waitcnt vmcnt(6)" ::: "memory");
  *(f16x8*)&Bls[0][0][woff] = cvt8(g0a, g0b);
  *(f16x8*)&Bls[0][1][woff] = cvt8(u0a, u0b);

#pragma unroll 2
  for (int kt = 0; kt < NK; ++kt) {
    const int b = kt & 1;
    // (a) issue B(kt+2) into slot b
    if (kt + 2 < NK) {
      const int k2 = (kt + 2) * 32;
      if (b == 0) {
        g0a = *(const f32x4*)(bgp + k2); g0b = *(const f32x4*)(bgp + k2 + 4);
        u0a = *(const f32x4*)(bup + k2); u0b = *(const f32x4*)(bup + k2 + 4);
      } else {
        g1a = *(const f32x4*)(bgp + k2); g1b = *(const f32x4*)(bgp + k2 + 4);
        u1a = *(const f32x4*)(bup + k2); u1b = *(const f32x4*)(bup + k2 + 4);
      }
    }
    __builtin_amdgcn_s_barrier();
    __builtin_amdgcn_sched_barrier(0);
    // (b) issue A(kt+1)
    if (kt + 1 < NK) issueA(kt + 1, b ^ 1);
    // (d) counted wait: retire B(kt+1) regs + A(kt) lds
    if (kt < NK - 2)       { asm volatile("s_waitcnt vmcnt(6)" ::: "memory"); }
    else if (kt == NK - 2) { asm volatile("s_waitcnt vmcnt(2)" ::: "memory"); }
    else                   { asm volatile("s_waitcnt vmcnt(0)" ::: "memory"); }
    // (e) cvt + ds_write B(kt+1)
    if (kt + 1 < NK) {
      if (b == 0) {
        *(f16x8*)&Bls[1][0][woff] = cvt8(g1a, g1b);
        *(f16x8*)&Bls[1][1][woff] = cvt8(u1a, u1b);
      } else {
        *(f16x8*)&Bls[0][0][woff] = cvt8(g0a, g0b);
        *(f16x8*)&Bls[0][1][woff] = cvt8(u0a, u0b);
      }
    }
    asm volatile("s_waitcnt lgkmcnt(0)" ::: "memory");
    __builtin_amdgcn_s_barrier();
    __builtin_amdgcn_sched_barrier(0);
    // (g) compute kt
    comp(b);
  }

  // epilogue: silu(g)*u -> fp16 h
  _Float16* hb = hbuf + (size_t)e * T_TOK * I_DIM;
#pragma unroll
  for (int m = 0; m < 4; ++m) {
#pragma unroll
    for (int j = 0; j < 4; ++j) {
      int r = row0 + wr * 64 + m * 16 + (lane >> 4) * 4 + j;
      if (r < ne) {
#pragma unroll
        for (int n = 0; n < 4; ++n) {
          int cc = col0 + wc * 64 + n * 16 + (lane & 15);
          float g = accg[m][n][j];
          float u = accu[m][n][j];
          float hv = (g / (1.f + __expf(-g))) * u;
          hb[(size_t)r * I_DIM + cc] = (_Float16)hv;
        }
      }
    }
  }
}

// ---------------- kernel 4: down GEMM, same pipeline + scatter-add ----------
// BM=256, BN=128, BK=32, 512 thr / 8 waves, wave tile 64x64. vmcnt(4) steady.
__global__ __launch_bounds__(512, 2) void down_kernel(
    const _Float16* __restrict__ hbuf, const float* __restrict__ wd,
    const int* __restrict__ counts, const int* __restrict__ lists,
    const float* __restrict__ coef, float* __restrict__ out) {
  const int e = blockIdx.z;
  const int ne = counts[e];
  const int row0 = blockIdx.y * 256;
  if (row0 >= ne) return;
  const int col0 = blockIdx.x * 128;
  const int tid = threadIdx.x;
  const int lane = tid & 63;
  const int w = tid >> 6;
  const int wr = w >> 1, wc = w & 1;

  __shared__ _Float16 Als[2][256 * 32];        // 32 KB
  __shared__ _Float16 Bls[2][128 * 32];        // 16 KB

  const _Float16* hb = hbuf + (size_t)e * T_TOK * I_DIM;
  const _Float16* ap0 = hb + (size_t)(row0 + (2 * w) * 16 + (lane & 15)) * I_DIM + (lane >> 4) * 8;
  const _Float16* ap1 = ap0 + (size_t)16 * I_DIM;
  const int adst0 = (2 * w) * 512 + lane * 8;
  const int adst1 = adst0 + 512;

  const int br = tid >> 2;
  const int bq = tid & 3;
  const float* bdp = wd + ((size_t)e * H_DIM + col0 + br) * I_DIM + bq * 8;
  const int woff = (br * 32 + bq * 8) ^ ((br & 7) << 3);

  f32x4 acc[4][4];
  const f32x4 zz = {0.f, 0.f, 0.f, 0.f};
#pragma unroll
  for (int m = 0; m < 4; ++m)
#pragma unroll
    for (int n = 0; n < 4; ++n) acc[m][n] = zz;

  auto issueA = [&](int kt, int b) {
    gload_lds16(ap0 + kt * 32, &Als[b][adst0]);
    gload_lds16(ap1 + kt * 32, &Als[b][adst1]);
  };
  auto comp = [&](int b) {
    f16x8 afr[4], bf[4];
#pragma unroll
    for (int m = 0; m < 4; ++m)
      afr[m] = *(const f16x8*)&Als[b][(wr * 4 + m) * 512 + lane * 8];
    const int sg = lane >> 4;
#pragma unroll
    for (int n = 0; n < 4; ++n) {
      const int c = wc * 64 + n * 16 + (lane & 15);
      const int off = (c * 32 + sg * 8) ^ ((c & 7) << 3);
      bf[n] = *(const f16x8*)&Bls[b][off];
    }
#pragma unroll
    for (int m = 0; m < 4; ++m)
#pragma unroll
      for (int n = 0; n < 4; ++n)
        acc[m][n] = __builtin_amdgcn_mfma_f32_16x16x32_f16(afr[m], bf[n], acc[m][n], 0, 0, 0);
  };

  const int NK = I_DIM / 32;   // 44
  f32x4 b0a, b0b, b1a, b1b;

  b0a = *(const f32x4*)(bdp);      b0b = *(const f32x4*)(bdp + 4);
  issueA(0, 0);
  b1a = *(const f32x4*)(bdp + 32); b1b = *(const f32x4*)(bdp + 36);
  asm volatile("s_waitcnt vmcnt(4)" ::: "memory");
  *(f16x8*)&Bls[0][woff] = cvt8(b0a, b0b);

#pragma unroll 2
  for (int kt = 0; kt < NK; ++kt) {
    const int b = kt & 1;
    if (kt + 2 < NK) {
      const int k2 = (kt + 2) * 32;
      if (b == 0) { b0a = *(const f32x4*)(bdp + k2); b0b = *(const f32x4*)(bdp + k2 + 4); }
      else        { b1a = *(const f32x4*)(bdp + k2); b1b = *(const f32x4*)(bdp + k2 + 4); }
    }
    __builtin_amdgcn_s_barrier();
    __builtin_amdgcn_sched_barrier(0);
    if (kt + 1 < NK) issueA(kt + 1, b ^ 1);
    if (kt < NK - 2)       { asm volatile("s_waitcnt vmcnt(4)" ::: "memory"); }
    else if (kt == NK - 2) { asm volatile("s_waitcnt vmcnt(2)" ::: "memory"); }
    else                   { asm volatile("s_waitcnt vmcnt(0)" ::: "memory"); }
    if (kt + 1 < NK) {
      if (b == 0) *(f16x8*)&Bls[1][woff] = cvt8(b1a, b1b);
      else        *(f16x8*)&Bls[0][woff] = cvt8(b0a, b0b);
    }
    asm volatile("s_waitcnt lgkmcnt(0)" ::: "memory");
    __builtin_amdgcn_s_barrier();
    __builtin_amdgcn_sched_barrier(0);
    comp(b);
  }

#pragma unroll
  for (int m = 0; m < 4; ++m) {
#pragma unroll
    for (int j = 0; j < 4; ++j) {
      int r = row0 + wr * 64 + m * 16 + (lane >> 4) * 4 + j;
      if (r < ne) {
        int tok = lists[e * T_TOK + r];
        float c = coef[tok * N_EXP + e];
#pragma unroll
        for (int n = 0; n < 4; ++n) {
          int cc = col0 + wc * 64 + n * 16 + (lane & 15);
          atomicAdd(&out[(size_t)tok * H_DIM + cc], acc[m][n][j] * c);
        }
      }
    }
  }
}

// ---------------- launch ----------------
extern "C" void kernel_launch(void* const* d_in, const int* in_sizes, int n_in,
                              void* d_out, int out_size, void* d_ws, size_t ws_size,
                              hipStream_t stream) {
  const float* x  = (const float*)d_in[0];
  const float* gw = (const float*)d_in[1];
  const float* cb = (const float*)d_in[2];
  const float* wg = (const float*)d_in[3];
  const float* wu = (const float*)d_in[4];
  const float* wd = (const float*)d_in[5];
  float* out = (float*)d_out;
  char* ws = (char*)d_ws;

  float* coef   = (float*)(ws);                    // 512*16*4 = 32768
  int*   counts = (int*)(ws + 32768);              // 64 B
  int*   lists  = (int*)(ws + 33024);              // 16*512*4 = 32768
  _Float16* xb  = (_Float16*)(ws + 66048);         // 512*2048*2 = 2 MiB
  _Float16* hbuf= (_Float16*)(ws + 66048 + 2097152 + 256); // 16*512*1408*2 = 23 MiB

  hipMemsetAsync(d_out, 0, (size_t)out_size * sizeof(float), stream);

  route_kernel<<<T_TOK, 256, 0, stream>>>(x, gw, cb, coef, xb);
  build_lists_kernel<<<N_EXP, 512, 0, stream>>>(coef, counts, lists);
  gate_up_kernel<<<dim3(I_DIM / 128, 2, N_EXP), 512, 0, stream>>>(xb, wg, wu, counts, lists, hbuf);
  down_kernel<<<dim3(H_DIM / 128, 2, N_EXP), 512, 0, stream>>>(hbuf, wd, counts, lists, coef, out);
}